// Round 12
// baseline (574.318 us; speedup 1.0000x reference)
//
#include <hip/hip_runtime.h>
#include <hip/hip_bf16.h>
#include <cstdint>
#include <cstddef>

typedef __attribute__((ext_vector_type(4))) float f32x4;
typedef __attribute__((ext_vector_type(8))) short short8;
typedef unsigned short ushort_t;

// ---- helpers ---------------------------------------------------------------
__device__ __forceinline__ ushort_t f2bf(float f) {
  return __builtin_bit_cast(ushort_t, __float2bfloat16(f));   // native RNE cast
}
__device__ __forceinline__ void load_lds16(const void* g, void* l) {
  __builtin_amdgcn_global_load_lds((const __attribute__((address_space(1))) void*)g,
                                   (__attribute__((address_space(3))) void*)l, 16, 0, 0);
}

// LDS byte-offset swizzles (applied identically on write and read)
__device__ __forceinline__ int swzA(int row, int b) { return row*128 + (b ^ ((row & 7) << 4)); }       // 128B rows
__device__ __forceinline__ int swzQ(int row, int b) { return row*64  + (b ^ (((row >> 1) & 3) << 4)); } // 64B rows
__device__ __forceinline__ int swzV(int d,   int b) { return d*256   + (b ^ ((d & 7) << 4)); }          // 256B rows

// ---- kernel 1: hidden f32 -> bf16 ------------------------------------------
__global__ __launch_bounds__(256) void k_cvt_bf16(const float4* __restrict__ in,
                                                  ushort_t* __restrict__ outp, int n4) {
  int i = blockIdx.x * 256 + threadIdx.x;
  int stride = gridDim.x * 256;
  for (; i < n4; i += stride) {
    float4 v = in[i];
    ushort4 o = { f2bf(v.x), f2bf(v.y), f2bf(v.z), f2bf(v.w) };
    *(ushort4*)(outp + (size_t)i * 4) = o;
  }
}

// ---- kernel 2: build head-grouped Wcat (bf16) + bcat (f32) -----------------
// Row order per head h: [q rows h*32..+32 | k rows | v rows]  (1536 rows of K=512)
__global__ __launch_bounds__(256) void k_wcat(const float* __restrict__ qw, const float* __restrict__ qb,
                                              const float* __restrict__ kw, const float* __restrict__ vw,
                                              const float* __restrict__ vb,
                                              ushort_t* __restrict__ Wcat, float* __restrict__ bcat) {
  int o = blockIdx.x;                   // 0..1535
  int h = o / 96, r = o % 96;
  const float* src; float bias;
  if (r < 32)      { src = qw + (size_t)(h*32 + r)      * 512; bias = qb[h*32 + r]; }
  else if (r < 64) { src = kw + (size_t)(h*32 + r - 32) * 512; bias = 0.f; }
  else             { src = vw + (size_t)(h*32 + r - 64) * 512; bias = vb[h*32 + r - 64]; }
  int t = threadIdx.x;
  Wcat[(size_t)o*512 + t]       = f2bf(src[t]);
  Wcat[(size_t)o*512 + t + 256] = f2bf(src[t + 256]);
  if (t == 0) bcat[o] = bias;
}

// ---- kernel 3: CPB MLP -> bias16[t][h] = 16*sigmoid(hbias) -----------------
__global__ __launch_bounds__(256) void k_bias(const float* __restrict__ w1, const float* __restrict__ b1,
                                              const float* __restrict__ w2, float* __restrict__ bias16) {
  int t = blockIdx.x;                   // 0..224 table rows
  int a = t / 15, b = t % 15;
  float x = (float)(a - 7) * (8.f / 7.f);
  float y = (float)(b - 7) * (8.f / 7.f);
  float fx = (x == 0.f) ? 0.f : copysignf(log2f(fabsf(x) + 1.f) * (1.f / 3.f), x);
  float fy = (y == 0.f) ? 0.f : copysignf(log2f(fabsf(y) + 1.f) * (1.f / 3.f), y);
  int wv = threadIdx.x >> 6, lane = threadIdx.x & 63;
  float acc[4] = {0.f, 0.f, 0.f, 0.f};
  for (int it = 0; it < 8; ++it) {
    int j = it*64 + lane;
    float act = fmaxf(fx * w1[2*j] + fy * w1[2*j + 1] + b1[j], 0.f);
#pragma unroll
    for (int hh = 0; hh < 4; ++hh)
      acc[hh] += act * w2[(wv*4 + hh)*512 + j];
  }
#pragma unroll
  for (int hh = 0; hh < 4; ++hh) {
    float v = acc[hh];
    for (int s = 1; s < 64; s <<= 1) v += __shfl_xor(v, s);
    if (lane == 0) bias16[t*16 + wv*4 + hh] = 16.f / (1.f + __expf(-v));
  }
}

// ---- kernel 4: fused QKV projection + cosine window attention --------------
// block = (mtile, head): 128 rows (= windows 2m, 2m+1) x 96 cols (q|k|v of head h)
// GEMM phase (BK=32, TRIPLE-buffered, ONE barrier/K-step, counted vmcnt):
//   A bufs [128][32] swzQ @ {0, 8K, 16K}; B bufs [96][32] swzQ @ {24K, 30K, 36K}
// attn phase (aliases, after post-loop barrier):
//   qs [128][32] @0 (8K, swzQ), ks [128][32] @8K (8K, swzQ),
//   vt [32][128] @16K (8K, swzV, V transposed),
//   ps DUAL: window win uses [64][64] swzA @ 24K + win*8K  (both alias dead
//   GEMM B-buffer space; disjoint regions let the two windows' chains overlap)
#define BBASE 24576
#define KS_OFF 8192
#define VT_OFF 16384
#define PS_OFF 24576

__global__ __launch_bounds__(256) void k_main(const ushort_t* __restrict__ hbf,
                                              const ushort_t* __restrict__ Wcat,
                                              const float* __restrict__ bcat,
                                              const float* __restrict__ bias16,
                                              const float* __restrict__ lscale,
                                              float* __restrict__ out) {
  __shared__ __align__(128) char lb_raw[43008];
  char* lb = lb_raw;

  int bid = blockIdx.x;
  int wg = (bid & 7) * 2048 + (bid >> 3);      // bijective XCD swizzle (16384 % 8 == 0)
  int mtile = wg >> 4;                         // 0..1023
  int h     = wg & 15;

  int tid = threadIdx.x;
  int w = tid >> 6, lane = tid & 63;
  int lm = lane & 15, lg = lane >> 4;

  const ushort_t* Ag = hbf  + (size_t)mtile * 128 * 512;
  const ushort_t* Wg = Wcat + (size_t)h * 96 * 512;

  // staging source offsets (elements), inverse-swizzled for swzQ 64B rows:
  // 1KB chunk c covers rows c*16 + (lane>>2), 16B slot s = lane&3.
  int rA0 = w*32      + (lane >> 2);           // A chunk w*2
  int rA1 = w*32 + 16 + (lane >> 2);           // A chunk w*2+1
  int rB0 = w*16      + (lane >> 2);           // B chunk w
  int rB1 = 64 + w*16 + (lane >> 2);           // B chunk 4+w (waves 0,1 only)
  int sl  = lane & 3;
  int offA0 = rA0*512 + (sl ^ ((rA0 >> 1) & 3))*8;
  int offA1 = rA1*512 + (sl ^ ((rA1 >> 1) & 3))*8;
  int offB0 = rB0*512 + (sl ^ ((rB0 >> 1) & 3))*8;
  int offB1 = rB1*512 + (sl ^ ((rB1 >> 1) & 3))*8;

  f32x4 acc[2][6] = {};

#define STAGE(ksn, bsel) do {                                                  \
    int kk0 = (ksn) * 32;                                                      \
    load_lds16(Ag + offA0 + kk0, lb + (bsel)*8192 + (w*2+0)*1024);             \
    load_lds16(Ag + offA1 + kk0, lb + (bsel)*8192 + (w*2+1)*1024);             \
    load_lds16(Wg + offB0 + kk0, lb + BBASE + (bsel)*6144 + w*1024);           \
    if (w < 2)                                                                 \
      load_lds16(Wg + offB1 + kk0, lb + BBASE + (bsel)*6144 + (4+w)*1024);     \
  } while (0)

  // ---- GEMM: 128x96 += A(128x512) * Wg^T, BK=32, 3-buf, 1 barrier/step -----
  // Safety: STAGE(t+1)->buf[(t+1)%3]; that buffer's last reader is MFMA(t-2),
  // separated by barrier(t-1) which precedes this STAGE issue in all waves.
  // buf[t%3] readiness: each wave drains its OWN stage(t) loads (counted
  // vmcnt) before barrier(t), so after barrier(t) all writes have landed.
  STAGE(0, 0);
#pragma unroll
  for (int ks = 0; ks < 16; ++ks) {
    int cur = ks % 3;
    if (ks < 15) {
      STAGE(ks + 1, (ks + 1) % 3);
      // drain stage(ks) only; stage(ks+1) stays in flight (counted, never 0)
      if (w < 2) asm volatile("s_waitcnt vmcnt(4)" ::: "memory");
      else       asm volatile("s_waitcnt vmcnt(3)" ::: "memory");
    } else {
      asm volatile("s_waitcnt vmcnt(0)" ::: "memory");
    }
    asm volatile("s_barrier" ::: "memory");    // raw: no compiler vmcnt(0) drain

    const char* Ab = lb + cur*8192;
    const char* Bb = lb + BBASE + cur*6144;
    short8 av0 = *(const short8*)(Ab + swzQ(w*32      + lm, lg*16));
    short8 av1 = *(const short8*)(Ab + swzQ(w*32 + 16 + lm, lg*16));
    short8 bv[6];
#pragma unroll
    for (int j = 0; j < 6; ++j)
      bv[j] = *(const short8*)(Bb + swzQ(j*16 + lm, lg*16));
#pragma unroll
    for (int j = 0; j < 6; ++j)
      acc[0][j] = __builtin_amdgcn_mfma_f32_16x16x32_bf16(av0, bv[j], acc[0][j], 0, 0, 0);
#pragma unroll
    for (int j = 0; j < 6; ++j)
      acc[1][j] = __builtin_amdgcn_mfma_f32_16x16x32_bf16(av1, bv[j], acc[1][j], 0, 0, 0);
    // no trailing barrier: 3-buffer rotation makes next STAGE safe
  }
#undef STAGE
  // epilogue below overwrites A-buf0 (qs) which step 15 just read:
  asm volatile("s_barrier" ::: "memory");

  // ---- relative-position bias fragment — hoisted so its 16 L1 loads fly
  //      under the epilogue's VALU (same for both windows) -------------------
  float bfrag[4][4];
#pragma unroll
  for (int ci = 0; ci < 4; ++ci) {
    int m = ci*16 + lm, rm = m >> 3, cm = m & 7;
#pragma unroll
    for (int r = 0; r < 4; ++r) {
      int n = w*16 + lg*4 + r;
      int idx = ((n >> 3) - rm + 7)*15 + ((n & 7) - cm + 7);
      bfrag[ci][r] = bias16[idx*16 + h];
    }
  }

  // ---- epilogue: bias + in-register normalize + write qs/ks/vt -------------
  // wave w owns rows w*32..w*32+32 (full q,k,v for those 32 tokens)
  __builtin_amdgcn_s_setprio(1);
  float scl = __expf(fminf(lscale[h], 4.6051701860f));   // exp(min(ls, ln 100))
  float bb[6];
#pragma unroll
  for (int nj = 0; nj < 6; ++nj) bb[nj] = bcat[h*96 + nj*16 + lm];

#pragma unroll
  for (int i = 0; i < 2; ++i) {
#pragma unroll
    for (int r = 0; r < 4; ++r) {
      float q0 = acc[i][0][r] + bb[0], q1 = acc[i][1][r] + bb[1];
      float k0 = acc[i][2][r],         k1 = acc[i][3][r];
      float ssq = q0*q0 + q1*q1;
      float ssk = k0*k0 + k1*k1;
      ssq += __shfl_xor(ssq, 1); ssq += __shfl_xor(ssq, 2);
      ssq += __shfl_xor(ssq, 4); ssq += __shfl_xor(ssq, 8);
      ssk += __shfl_xor(ssk, 1); ssk += __shfl_xor(ssk, 2);
      ssk += __shfl_xor(ssk, 4); ssk += __shfl_xor(ssk, 8);
      float rq = rsqrtf(ssq) * scl;     // fold logit scale into qn
      float rk = rsqrtf(ssk);
      int row = w*32 + i*16 + lg*4 + r;
      *(ushort_t*)(lb + swzQ(row, lm*2))                  = f2bf(q0 * rq);
      *(ushort_t*)(lb + swzQ(row, 32 + lm*2))             = f2bf(q1 * rq);
      *(ushort_t*)(lb + KS_OFF + swzQ(row, lm*2))         = f2bf(k0 * rk);
      *(ushort_t*)(lb + KS_OFF + swzQ(row, 32 + lm*2))    = f2bf(k1 * rk);
    }
    // V^T: 4 consecutive tokens -> one swizzled b64 store (no 16-way conflict)
#pragma unroll
    for (int j = 0; j < 2; ++j) {
      ushort4 pk;
      pk.x = f2bf(acc[i][4+j][0] + bb[4+j]);
      pk.y = f2bf(acc[i][4+j][1] + bb[4+j]);
      pk.z = f2bf(acc[i][4+j][2] + bb[4+j]);
      pk.w = f2bf(acc[i][4+j][3] + bb[4+j]);
      int d = j*16 + lm, tokb = (w*32 + i*16 + lg*4) * 2;
      *(ushort4*)(lb + VT_OFF + swzV(d, tokb)) = pk;
    }
  }
  __syncthreads();

  // ---- attention: wave w owns rows [16w,16w+16) of each window -------------
  // dual ps: window win's P lives at PS_OFF + win*8192 (disjoint regions, no
  // WAR between windows -> the two windows' chains can overlap)
#pragma unroll
  for (int win = 0; win < 2; ++win) {
    char* ps = lb + PS_OFF + win*8192;
    short8 aq = *(const short8*)(lb + swzQ(win*64 + w*16 + lm, lg*16));
    f32x4 p[4];
#pragma unroll
    for (int ci = 0; ci < 4; ++ci) {
      short8 bk = *(const short8*)(lb + KS_OFF + swzQ(win*64 + ci*16 + lm, lg*16));
      f32x4 z = {0.f, 0.f, 0.f, 0.f};
      f32x4 s = __builtin_amdgcn_mfma_f32_16x16x32_bf16(aq, bk, z, 0, 0, 0);
#pragma unroll
      for (int r = 0; r < 4; ++r)
        p[ci][r] = __expf(s[r] + bfrag[ci][r]);   // no max-sub: |arg| <= 26, f32-safe
    }
    // store UNNORMALIZED P immediately (1/sum folded into PV output below);
    // row-sum shfl chain overlaps these stores' latency.
#pragma unroll
    for (int ci = 0; ci < 4; ++ci)
#pragma unroll
      for (int r = 0; r < 4; ++r) {
        int row = w*16 + lg*4 + r;
        *(ushort_t*)(ps + swzA(row, (ci*16 + lm)*2)) = f2bf(p[ci][r]);
      }
    float rs[4];
#pragma unroll
    for (int r = 0; r < 4; ++r) {
      float s = p[0][r] + p[1][r] + p[2][r] + p[3][r];
      s += __shfl_xor(s, 1); s += __shfl_xor(s, 2);
      s += __shfl_xor(s, 4); s += __shfl_xor(s, 8);
      rs[r] = 1.f / s;
    }
    // PV: O(16x32) = P(16x64) @ V(64x32)  (wave-private P rows, in-order LDS)
    f32x4 oacc[2] = {};
#pragma unroll
    for (int kk = 0; kk < 2; ++kk) {
      short8 ap = *(const short8*)(ps + swzA(w*16 + lm, kk*64 + lg*16));
#pragma unroll
      for (int ci = 0; ci < 2; ++ci) {
        short8 bvv = *(const short8*)(lb + VT_OFF + swzV(ci*16 + lm, win*128 + kk*64 + lg*16));
        oacc[ci] = __builtin_amdgcn_mfma_f32_16x16x32_bf16(ap, bvv, oacc[ci], 0, 0, 0);
      }
    }
    size_t gw = (size_t)mtile*2 + win;
#pragma unroll
    for (int ci = 0; ci < 2; ++ci)
#pragma unroll
      for (int r = 0; r < 4; ++r) {
        int n = w*16 + lg*4 + r;
        out[(gw*64 + n)*512 + h*32 + ci*16 + lm] = oacc[ci][r] * rs[r];
      }
  }
  __builtin_amdgcn_s_setprio(0);
}

// ---- launcher ---------------------------------------------------------------
extern "C" void kernel_launch(void* const* d_in, const int* in_sizes, int n_in,
                              void* d_out, int out_size, void* d_ws, size_t ws_size,
                              hipStream_t stream) {
  (void)in_sizes; (void)n_in; (void)out_size; (void)ws_size;
  const float* hidden = (const float*)d_in[0];
  const float* q_w    = (const float*)d_in[1];
  const float* q_b    = (const float*)d_in[2];
  const float* k_w    = (const float*)d_in[3];
  const float* v_w    = (const float*)d_in[4];
  const float* v_b    = (const float*)d_in[5];
  const float* lscale = (const float*)d_in[6];
  const float* cpb_w1 = (const float*)d_in[7];
  const float* cpb_b1 = (const float*)d_in[8];
  const float* cpb_w2 = (const float*)d_in[9];
  float* out = (float*)d_out;

  char* wsb = (char*)d_ws;
  ushort_t* hbf    = (ushort_t*)wsb;                        // 134,217,728 B
  ushort_t* Wcat   = (ushort_t*)(wsb + 134217728);          //   1,572,864 B
  float*    bcat   = (float*)(wsb + 135790592);             //       6,144 B
  float*    bias16 = (float*)(wsb + 135796736);             //      14,400 B

  hipLaunchKernelGGL(k_cvt_bf16, dim3(2048), dim3(256), 0, stream,
                     (const float4*)hidden, hbf, 16777216);
  hipLaunchKernelGGL(k_wcat, dim3(1536), dim3(256), 0, stream,
                     q_w, q_b, k_w, v_w, v_b, Wcat, bcat);
  hipLaunchKernelGGL(k_bias, dim3(225), dim3(256), 0, stream,
                     cpb_w1, cpb_b1, cpb_w2, bias16);
  hipLaunchKernelGGL(k_main, dim3(16384), dim3(256), 0, stream,
                     hbf, Wcat, bcat, bias16, lscale, out);
}

// Round 13
// 467.259 us; speedup vs baseline: 1.2291x; 1.2291x over previous
//
#include <hip/hip_runtime.h>
#include <hip/hip_bf16.h>
#include <cstdint>
#include <cstddef>

typedef __attribute__((ext_vector_type(4))) float f32x4;
typedef __attribute__((ext_vector_type(8))) short short8;
typedef unsigned short ushort_t;

// ---- helpers ---------------------------------------------------------------
__device__ __forceinline__ ushort_t f2bf(float f) {
  return __builtin_bit_cast(ushort_t, __float2bfloat16(f));   // native RNE cast
}
__device__ __forceinline__ void load_lds16(const void* g, void* l) {
  __builtin_amdgcn_global_load_lds((const __attribute__((address_space(1))) void*)g,
                                   (__attribute__((address_space(3))) void*)l, 16, 0, 0);
}

#define LOG2E 1.4426950408889634f

// LDS byte-offset swizzles (applied identically on write and read)
__device__ __forceinline__ int swzA(int row, int b) { return row*128 + (b ^ ((row & 7) << 4)); }       // 128B rows
__device__ __forceinline__ int swzQ(int row, int b) { return row*64  + (b ^ (((row >> 1) & 3) << 4)); } // 64B rows
__device__ __forceinline__ int swzV(int d,   int b) { return d*256   + (b ^ ((d & 7) << 4)); }          // 256B rows

// ---- kernel 1: hidden f32 -> bf16 ------------------------------------------
__global__ __launch_bounds__(256) void k_cvt_bf16(const float4* __restrict__ in,
                                                  ushort_t* __restrict__ outp, int n4) {
  int i = blockIdx.x * 256 + threadIdx.x;
  int stride = gridDim.x * 256;
  for (; i < n4; i += stride) {
    float4 v = in[i];
    ushort4 o = { f2bf(v.x), f2bf(v.y), f2bf(v.z), f2bf(v.w) };
    *(ushort4*)(outp + (size_t)i * 4) = o;
  }
}

// ---- kernel 2: build head-grouped Wcat (bf16) + bcat (f32) -----------------
// Row order per head h: [q rows h*32..+32 | k rows | v rows]  (1536 rows of K=512)
__global__ __launch_bounds__(256) void k_wcat(const float* __restrict__ qw, const float* __restrict__ qb,
                                              const float* __restrict__ kw, const float* __restrict__ vw,
                                              const float* __restrict__ vb,
                                              ushort_t* __restrict__ Wcat, float* __restrict__ bcat) {
  int o = blockIdx.x;                   // 0..1535
  int h = o / 96, r = o % 96;
  const float* src; float bias;
  if (r < 32)      { src = qw + (size_t)(h*32 + r)      * 512; bias = qb[h*32 + r]; }
  else if (r < 64) { src = kw + (size_t)(h*32 + r - 32) * 512; bias = 0.f; }
  else             { src = vw + (size_t)(h*32 + r - 64) * 512; bias = vb[h*32 + r - 64]; }
  int t = threadIdx.x;
  Wcat[(size_t)o*512 + t]       = f2bf(src[t]);
  Wcat[(size_t)o*512 + t + 256] = f2bf(src[t + 256]);
  if (t == 0) bcat[o] = bias;
}

// ---- kernel 3: CPB MLP -> bias16[t][h] = 16*sigmoid(hbias)*log2e -----------
__global__ __launch_bounds__(256) void k_bias(const float* __restrict__ w1, const float* __restrict__ b1,
                                              const float* __restrict__ w2, float* __restrict__ bias16) {
  int t = blockIdx.x;                   // 0..224 table rows
  int a = t / 15, b = t % 15;
  float x = (float)(a - 7) * (8.f / 7.f);
  float y = (float)(b - 7) * (8.f / 7.f);
  float fx = (x == 0.f) ? 0.f : copysignf(log2f(fabsf(x) + 1.f) * (1.f / 3.f), x);
  float fy = (y == 0.f) ? 0.f : copysignf(log2f(fabsf(y) + 1.f) * (1.f / 3.f), y);
  int wv = threadIdx.x >> 6, lane = threadIdx.x & 63;
  float acc[4] = {0.f, 0.f, 0.f, 0.f};
  for (int it = 0; it < 8; ++it) {
    int j = it*64 + lane;
    float act = fmaxf(fx * w1[2*j] + fy * w1[2*j + 1] + b1[j], 0.f);
#pragma unroll
    for (int hh = 0; hh < 4; ++hh)
      acc[hh] += act * w2[(wv*4 + hh)*512 + j];
  }
#pragma unroll
  for (int hh = 0; hh < 4; ++hh) {
    float v = acc[hh];
    for (int s = 1; s < 64; s <<= 1) v += __shfl_xor(v, s);
    if (lane == 0) bias16[t*16 + wv*4 + hh] = LOG2E * 16.f / (1.f + __expf(-v));
  }
}

// ---- kernel 4: fused QKV projection + cosine window attention --------------
// block = (mtile, head): 128 rows (= windows 2m, 2m+1) x 96 cols (q|k|v of head h)
// GEMM phase (BK=32, TRIPLE-buffered, ONE barrier/K-step, counted vmcnt):
//   A bufs [128][32] swzQ @ {0, 8K, 16K}; B bufs [96][32] swzQ @ {24K, 30K, 36K}
// attn phase (aliases, after post-loop barrier):
//   qs [128][32] @0 (8K, swzQ), ks [128][32] @8K (8K, swzQ),
//   vt [32][128] @16K (8K, swzV, V transposed), ps [64][64] @24K (8K, swzA)
#define BBASE 24576
#define KS_OFF 8192
#define VT_OFF 16384
#define PS_OFF 24576

__global__ __launch_bounds__(256) void k_main(const ushort_t* __restrict__ hbf,
                                              const ushort_t* __restrict__ Wcat,
                                              const float* __restrict__ bcat,
                                              const float* __restrict__ bias16,
                                              const float* __restrict__ lscale,
                                              float* __restrict__ out) {
  __shared__ __align__(128) char lb_raw[43008];
  char* lb = lb_raw;

  int bid = blockIdx.x;
  int wg = (bid & 7) * 2048 + (bid >> 3);      // bijective XCD swizzle (16384 % 8 == 0)
  int mtile = wg >> 4;                         // 0..1023
  int h     = wg & 15;

  int tid = threadIdx.x;
  int w = tid >> 6, lane = tid & 63;
  int lm = lane & 15, lg = lane >> 4;

  const ushort_t* Ag = hbf  + (size_t)mtile * 128 * 512;
  const ushort_t* Wg = Wcat + (size_t)h * 96 * 512;

  // staging source offsets (elements), inverse-swizzled for swzQ 64B rows:
  // 1KB chunk c covers rows c*16 + (lane>>2), 16B slot s = lane&3.
  int rA0 = w*32      + (lane >> 2);           // A chunk w*2
  int rA1 = w*32 + 16 + (lane >> 2);           // A chunk w*2+1
  int rB0 = w*16      + (lane >> 2);           // B chunk w
  int rB1 = 64 + w*16 + (lane >> 2);           // B chunk 4+w (waves 0,1 only)
  int sl  = lane & 3;
  int offA0 = rA0*512 + (sl ^ ((rA0 >> 1) & 3))*8;
  int offA1 = rA1*512 + (sl ^ ((rA1 >> 1) & 3))*8;
  int offB0 = rB0*512 + (sl ^ ((rB0 >> 1) & 3))*8;
  int offB1 = rB1*512 + (sl ^ ((rB1 >> 1) & 3))*8;

  f32x4 acc[2][6] = {};

#define STAGE(ksn, bsel) do {                                                  \
    int kk0 = (ksn) * 32;                                                      \
    load_lds16(Ag + offA0 + kk0, lb + (bsel)*8192 + (w*2+0)*1024);             \
    load_lds16(Ag + offA1 + kk0, lb + (bsel)*8192 + (w*2+1)*1024);             \
    load_lds16(Wg + offB0 + kk0, lb + BBASE + (bsel)*6144 + w*1024);           \
    if (w < 2)                                                                 \
      load_lds16(Wg + offB1 + kk0, lb + BBASE + (bsel)*6144 + (4+w)*1024);     \
  } while (0)

  // ---- GEMM: 128x96 += A(128x512) * Wg^T, BK=32, 3-buf, 1 barrier/step -----
  // Safety: STAGE(t+1)->buf[(t+1)%3]; that buffer's last reader is MFMA(t-2),
  // separated by barrier(t-1) which precedes this STAGE issue in all waves.
  // buf[t%3] readiness: each wave drains its OWN stage(t) loads (counted
  // vmcnt) before barrier(t), so after barrier(t) all writes have landed.
  STAGE(0, 0);
#pragma unroll
  for (int ks = 0; ks < 16; ++ks) {
    int cur = ks % 3;
    if (ks < 15) {
      STAGE(ks + 1, (ks + 1) % 3);
      // drain stage(ks) only; stage(ks+1) stays in flight (counted, never 0)
      if (w < 2) asm volatile("s_waitcnt vmcnt(4)" ::: "memory");
      else       asm volatile("s_waitcnt vmcnt(3)" ::: "memory");
    } else {
      asm volatile("s_waitcnt vmcnt(0)" ::: "memory");
    }
    asm volatile("s_barrier" ::: "memory");    // raw: no compiler vmcnt(0) drain

    const char* Ab = lb + cur*8192;
    const char* Bb = lb + BBASE + cur*6144;
    short8 av0 = *(const short8*)(Ab + swzQ(w*32      + lm, lg*16));
    short8 av1 = *(const short8*)(Ab + swzQ(w*32 + 16 + lm, lg*16));
    short8 bv[6];
#pragma unroll
    for (int j = 0; j < 6; ++j)
      bv[j] = *(const short8*)(Bb + swzQ(j*16 + lm, lg*16));
#pragma unroll
    for (int j = 0; j < 6; ++j)
      acc[0][j] = __builtin_amdgcn_mfma_f32_16x16x32_bf16(av0, bv[j], acc[0][j], 0, 0, 0);
#pragma unroll
    for (int j = 0; j < 6; ++j)
      acc[1][j] = __builtin_amdgcn_mfma_f32_16x16x32_bf16(av1, bv[j], acc[1][j], 0, 0, 0);
    // no trailing barrier: 3-buffer rotation makes next STAGE safe
  }
#undef STAGE
  // epilogue below overwrites A-buf0 (qs) which step 15 just read:
  asm volatile("s_barrier" ::: "memory");

  // ---- epilogue: bias + in-register normalize + write qs/ks/vt -------------
  // wave w owns rows w*32..w*32+32 (full q,k,v for those 32 tokens)
  // log2e folded into q-normalizer: QK^T output is already in exp2 domain.
  float scl = __expf(fminf(lscale[h], 4.6051701860f)) * LOG2E;
  float bb[6];
#pragma unroll
  for (int nj = 0; nj < 6; ++nj) bb[nj] = bcat[h*96 + nj*16 + lm];

#pragma unroll
  for (int i = 0; i < 2; ++i) {
#pragma unroll
    for (int r = 0; r < 4; ++r) {
      float q0 = acc[i][0][r] + bb[0], q1 = acc[i][1][r] + bb[1];
      float k0 = acc[i][2][r],         k1 = acc[i][3][r];
      float ssq = q0*q0 + q1*q1;
      float ssk = k0*k0 + k1*k1;
      ssq += __shfl_xor(ssq, 1); ssq += __shfl_xor(ssq, 2);
      ssq += __shfl_xor(ssq, 4); ssq += __shfl_xor(ssq, 8);
      ssk += __shfl_xor(ssk, 1); ssk += __shfl_xor(ssk, 2);
      ssk += __shfl_xor(ssk, 4); ssk += __shfl_xor(ssk, 8);
      float rq = rsqrtf(ssq) * scl;     // fold logit scale + log2e into qn
      float rk = rsqrtf(ssk);
      int row = w*32 + i*16 + lg*4 + r;
      *(ushort_t*)(lb + swzQ(row, lm*2))                  = f2bf(q0 * rq);
      *(ushort_t*)(lb + swzQ(row, 32 + lm*2))             = f2bf(q1 * rq);
      *(ushort_t*)(lb + KS_OFF + swzQ(row, lm*2))         = f2bf(k0 * rk);
      *(ushort_t*)(lb + KS_OFF + swzQ(row, 32 + lm*2))    = f2bf(k1 * rk);
    }
    // V^T: 4 consecutive tokens -> one swizzled b64 store (no 16-way conflict)
#pragma unroll
    for (int j = 0; j < 2; ++j) {
      ushort4 pk;
      pk.x = f2bf(acc[i][4+j][0] + bb[4+j]);
      pk.y = f2bf(acc[i][4+j][1] + bb[4+j]);
      pk.z = f2bf(acc[i][4+j][2] + bb[4+j]);
      pk.w = f2bf(acc[i][4+j][3] + bb[4+j]);
      int d = j*16 + lm, tokb = (w*32 + i*16 + lg*4) * 2;
      *(ushort4*)(lb + VT_OFF + swzV(d, tokb)) = pk;
    }
  }
  __syncthreads();

  // ---- relative-position bias fragment (L1-hot 14.4 KB table; same for both
  //      windows since idx depends only on in-window coords) -----------------
  float bfrag[4][4];
#pragma unroll
  for (int ci = 0; ci < 4; ++ci) {
    int m = ci*16 + lm, rm = m >> 3, cm = m & 7;
#pragma unroll
    for (int r = 0; r < 4; ++r) {
      int n = w*16 + lg*4 + r;
      int idx = ((n >> 3) - rm + 7)*15 + ((n & 7) - cm + 7);
      bfrag[ci][r] = bias16[idx*16 + h];
    }
  }

  // ---- attention: wave w owns rows [16w,16w+16) of each window -------------
#pragma unroll
  for (int win = 0; win < 2; ++win) {
    short8 aq = *(const short8*)(lb + swzQ(win*64 + w*16 + lm, lg*16));
    f32x4 p[4];
#pragma unroll
    for (int ci = 0; ci < 4; ++ci) {
      short8 bk = *(const short8*)(lb + KS_OFF + swzQ(win*64 + ci*16 + lm, lg*16));
      f32x4 z = {0.f, 0.f, 0.f, 0.f};
      f32x4 s = __builtin_amdgcn_mfma_f32_16x16x32_bf16(aq, bk, z, 0, 0, 0);
#pragma unroll
      for (int r = 0; r < 4; ++r)
        p[ci][r] = __builtin_amdgcn_exp2f(s[r] + bfrag[ci][r]);  // exp2 domain; |arg|<=38, f32-safe
    }
    // store UNNORMALIZED P immediately (1/sum folded into PV output below);
    // row-sum shfl chain overlaps these stores' latency.
#pragma unroll
    for (int ci = 0; ci < 4; ++ci)
#pragma unroll
      for (int r = 0; r < 4; ++r) {
        int row = w*16 + lg*4 + r;
        *(ushort_t*)(lb + PS_OFF + swzA(row, (ci*16 + lm)*2)) = f2bf(p[ci][r]);
      }
    float rs[4];
#pragma unroll
    for (int r = 0; r < 4; ++r) {
      float s = p[0][r] + p[1][r] + p[2][r] + p[3][r];
      s += __shfl_xor(s, 1); s += __shfl_xor(s, 2);
      s += __shfl_xor(s, 4); s += __shfl_xor(s, 8);
      rs[r] = 1.f / s;
    }
    // PV: O(16x32) = P(16x64) @ V(64x32)  (wave-private P rows, in-order LDS)
    f32x4 oacc[2] = {};
#pragma unroll
    for (int kk = 0; kk < 2; ++kk) {
      short8 ap = *(const short8*)(lb + PS_OFF + swzA(w*16 + lm, kk*64 + lg*16));
#pragma unroll
      for (int ci = 0; ci < 2; ++ci) {
        short8 bvv = *(const short8*)(lb + VT_OFF + swzV(ci*16 + lm, win*128 + kk*64 + lg*16));
        oacc[ci] = __builtin_amdgcn_mfma_f32_16x16x32_bf16(ap, bvv, oacc[ci], 0, 0, 0);
      }
    }
    size_t gw = (size_t)mtile*2 + win;
#pragma unroll
    for (int ci = 0; ci < 2; ++ci)
#pragma unroll
      for (int r = 0; r < 4; ++r) {
        int n = w*16 + lg*4 + r;
        out[(gw*64 + n)*512 + h*32 + ci*16 + lm] = oacc[ci][r] * rs[r];
      }
  }
}

// ---- launcher ---------------------------------------------------------------
extern "C" void kernel_launch(void* const* d_in, const int* in_sizes, int n_in,
                              void* d_out, int out_size, void* d_ws, size_t ws_size,
                              hipStream_t stream) {
  (void)in_sizes; (void)n_in; (void)out_size; (void)ws_size;
  const float* hidden = (const float*)d_in[0];
  const float* q_w    = (const float*)d_in[1];
  const float* q_b    = (const float*)d_in[2];
  const float* k_w    = (const float*)d_in[3];
  const float* v_w    = (const float*)d_in[4];
  const float* v_b    = (const float*)d_in[5];
  const float* lscale = (const float*)d_in[6];
  const float* cpb_w1 = (const float*)d_in[7];
  const float* cpb_b1 = (const float*)d_in[8];
  const float* cpb_w2 = (const float*)d_in[9];
  float* out = (float*)d_out;

  char* wsb = (char*)d_ws;
  ushort_t* hbf    = (ushort_t*)wsb;                        // 134,217,728 B
  ushort_t* Wcat   = (ushort_t*)(wsb + 134217728);          //   1,572,864 B
  float*    bcat   = (float*)(wsb + 135790592);             //       6,144 B
  float*    bias16 = (float*)(wsb + 135796736);             //      14,400 B

  hipLaunchKernelGGL(k_cvt_bf16, dim3(2048), dim3(256), 0, stream,
                     (const float4*)hidden, hbf, 16777216);
  hipLaunchKernelGGL(k_wcat, dim3(1536), dim3(256), 0, stream,
                     q_w, q_b, k_w, v_w, v_b, Wcat, bcat);
  hipLaunchKernelGGL(k_bias, dim3(225), dim3(256), 0, stream,
                     cpb_w1, cpb_b1, cpb_w2, bias16);
  hipLaunchKernelGGL(k_main, dim3(16384), dim3(256), 0, stream,
                     hbf, Wcat, bcat, bias16, lscale, out);
}